// Round 4
// baseline (289.650 us; speedup 1.0000x reference)
//
#include <hip/hip_runtime.h>

#define NBATCH 32
#define NFEAT 48
#define C1c 6
#define LRC 42
#define HH 128
#define WW 128
#define HWSZ 16384
#define NP 81
#define NQ 64

// workspace layout (in floats)
#define OFF_PM   0                      // 81*64 = 5184
#define OFF_GAP  5184                   // 32*42 = 1344
#define OFF_K    6528                   // 64*64 = 4096
#define OFF_ATTN 10624                  // 1344
#define OFF_WB   11968                  // 48*48 = 2304 rearranged weights
#define OFF_HR   14272                  // 32*6*16384 = 3145728

// ---------------- Phase 1 (merged): softmax->pm binning  +  gap sums ----------------
__global__ __launch_bounds__(256, 2) void k_phase1(const float* __restrict__ logits,
                                                   const float* __restrict__ feat,
                                                   float* __restrict__ pm_sum,
                                                   float* __restrict__ gap) {
    int bid = blockIdx.x;
    int tid = threadIdx.x;
    if (bid < 512) {
        // per-pixel softmax over 81 ch, binned into pm_sum[81][64]
        int b   = bid >> 4;
        int ygp = (bid >> 2) & 3;
        int qq  = bid & 3;
        int x   = tid & 127;
        int yg  = ygp * 2 + (tid >> 7);
        float acc[NP];
#pragma unroll
        for (int p = 0; p < NP; ++p) acc[p] = 0.f;
        for (int k = 0; k < 4; ++k) {
            int y = yg + 8 * (qq * 4 + k);
            const float* base = logits + (size_t)b * NP * HWSZ + (y << 7) + x;
            float ev[NP];
            float s = 0.f;
#pragma unroll
            for (int p = 0; p < NP; ++p) { ev[p] = __expf(base[(size_t)p * HWSZ]); s += ev[p]; }
            float inv = 1.f / s;
#pragma unroll
            for (int p = 0; p < NP; ++p) acc[p] += ev[p] * inv;
        }
        int lane = tid & 63;
#pragma unroll
        for (int p = 0; p < NP; ++p) {
            float e = acc[p];
            e += __shfl_xor(e, 8);
            e += __shfl_xor(e, 16);
            e += __shfl_xor(e, 32);
            if (lane < 8) atomicAdd(&pm_sum[p * NQ + (yg << 3) + lane], e);
        }
    } else {
        // gap_sum[b][c] = sum over HxW of feat[b, 6+c]
        int gid = bid - 512;
        int b = gid / LRC, c = gid % LRC;
        const float4* p4 = (const float4*)(feat + ((size_t)b * NFEAT + C1c + c) * HWSZ);
        float s = 0.f;
        for (int i = tid; i < HWSZ / 4; i += 256) {
            float4 v = p4[i];
            s += (v.x + v.y) + (v.z + v.w);
        }
        s += __shfl_xor(s, 1);  s += __shfl_xor(s, 2);  s += __shfl_xor(s, 4);
        s += __shfl_xor(s, 8);  s += __shfl_xor(s, 16); s += __shfl_xor(s, 32);
        __shared__ float w4[4];
        if ((tid & 63) == 0) w4[tid >> 6] = s;
        __syncthreads();
        if (tid == 0) gap[gid] = w4[0] + w4[1] + w4[2] + w4[3];
    }
}

// ---------------- K3: build K (64x64), attn (32x42), and rearranged weights wbuf[48][48] ----------------
__global__ __launch_bounds__(256) void k_small(const float* __restrict__ pm_sum,
                                               const float* __restrict__ gap_sum,
                                               const float* __restrict__ sigx,
                                               const float* __restrict__ sigy,
                                               const float* __restrict__ opac,
                                               const float* __restrict__ rho,
                                               const float* __restrict__ w_v2,
                                               const float* __restrict__ w_fine,
                                               const float* __restrict__ w_res,
                                               float* __restrict__ Kmat,
                                               float* __restrict__ attn,
                                               float* __restrict__ wbuf) {
    int tid = threadIdx.x;
    if (tid < 64) {
        int q = tid;
        float wsx = 0.f, wsy = 0.f, wop = 0.f, wr = 0.f;
        for (int p = 0; p < NP; ++p) {
            float pv = pm_sum[p * NQ + q] * (1.f / 8192.f);
            wsx += sigx[p] * pv;
            wsy += sigy[p] * pv;
            wop += opac[p] * pv;
            wr  += rho[p]  * pv;
        }
        float a = wsx * wsx, d = wsy * wsy, bc = wr * wsx * wsy;
        float det = a * d - bc * bc;
        float i00 = d / det, i01 = -bc / det, i11 = a / det;
        int iq = q >> 3, jq = q & 7;
        for (int h = 0; h < 8; ++h)
            for (int w = 0; w < 8; ++w) {
                int ki = h - iq + 2, kj = w - jq + 2;
                float val = 0.f;
                if (ki >= 0 && ki < 5 && kj >= 0 && kj < 5) {
                    float xx = -5.f + 2.5f * ki, yy = -5.f + 2.5f * kj;
                    val = wop * __expf(-0.5f * (i00 * xx * xx + 2.f * i01 * xx * yy + i11 * yy * yy));
                }
                Kmat[(q << 6) + (h << 3) + w] = val;
            }
    }
    for (int i = tid; i < NBATCH * LRC; i += 256) {
        int b = i / LRC, co = i % LRC;
        float s = 0.f;
        for (int ci = 0; ci < LRC; ++ci) s += w_v2[co * LRC + ci] * gap_sum[b * LRC + ci];
        s *= (1.f / 16384.f);
        attn[i] = 1.f / (1.f + __expf(-s));
    }
    // wbuf[c*48 + o*9 + t] = w_fine[o][c][t];  wbuf[c*48 + 36 + o] = w_res[o][c]
    for (int i = tid; i < NFEAT * 48; i += 256) {
        int c = i / 48, j = i - c * 48;
        float v = 0.f;
        if (j < 36) v = w_fine[(j / 9) * (NFEAT * 9) + c * 9 + (j % 9)];
        else if (j < 40) v = w_res[(j - 36) * NFEAT + c];
        wbuf[i] = v;
    }
}

// ---------------- K4: hr = (colors @ K) * V1 ----------------
// grid 512 = b(32) * strip(8 of 16 rows) * chalf(2 of 3 channels); 2 blocks/CU.
// K staged in LDS with group-stride 12 (16B aligned, conflict-free b128 across hrow).
__global__ __launch_bounds__(256) void k_hr(const float* __restrict__ feat,
                                            const float* __restrict__ V,
                                            const float* __restrict__ Kmat,
                                            float* __restrict__ hr) {
    __shared__ __align__(16) float lK[64 * 96];     // [q][h*12 + j], j<8 used
    __shared__ __align__(16) float lF[3 * 16 * 128];
    int bid   = blockIdx.x;
    int b     = bid >> 4;
    int strip = (bid >> 1) & 7;
    int ch    = (bid & 1) * 3;
    int y0    = strip << 4;
    int tid   = threadIdx.x;
    for (int i = tid; i < 4096; i += 256) {
        int q = i >> 6, hj = i & 63;
        lK[q * 96 + (hj >> 3) * 12 + (hj & 7)] = Kmat[i];
    }
    for (int i = tid; i < 6144; i += 256) {
        int c = i >> 11, rem = i & 2047;
        lF[i] = feat[(((size_t)b * NFEAT + ch + c) << 14) + (((size_t)y0 + (rem >> 7)) << 7) + (rem & 127)];
    }
    __syncthreads();
    int tile = tid >> 3, hrow = tid & 7;
    int tr = tile >> 4, tx = tile & 15;
    float acc[3][8];
#pragma unroll
    for (int c = 0; c < 3; ++c)
#pragma unroll
        for (int j = 0; j < 8; ++j) acc[c][j] = 0.f;
    int fbase = (tr << 3) * 128 + (tx << 3);
    for (int q = 0; q < 64; ++q) {
        int iq = q >> 3, jq = q & 7;
        const float4 k0 = *(const float4*)&lK[q * 96 + hrow * 12];
        const float4 k1 = *(const float4*)&lK[q * 96 + hrow * 12 + 4];
#pragma unroll
        for (int c = 0; c < 3; ++c) {
            float col = lF[(c << 11) + fbase + (iq << 7) + jq];
            acc[c][0] += col * k0.x; acc[c][1] += col * k0.y;
            acc[c][2] += col * k0.z; acc[c][3] += col * k0.w;
            acc[c][4] += col * k1.x; acc[c][5] += col * k1.y;
            acc[c][6] += col * k1.z; acc[c][7] += col * k1.w;
        }
    }
    int y = y0 + (tr << 3) + hrow;
#pragma unroll
    for (int c = 0; c < 3; ++c) {
        const float4* vp = (const float4*)(V + (((size_t)b * NFEAT + ch + c) << 14) + ((size_t)y << 7) + (tx << 3));
        float4 v0 = vp[0], v1 = vp[1];
        float4 r0, r1;
        r0.x = acc[c][0] * v0.x; r0.y = acc[c][1] * v0.y; r0.z = acc[c][2] * v0.z; r0.w = acc[c][3] * v0.w;
        r1.x = acc[c][4] * v1.x; r1.y = acc[c][5] * v1.y; r1.z = acc[c][6] * v1.z; r1.w = acc[c][7] * v1.w;
        float4* op = (float4*)(hr + (((size_t)b * C1c + ch + c) << 14) + ((size_t)y << 7) + (tx << 3));
        op[0] = r0; op[1] = r1;
    }
}

// ---------------- K5: fused conv3x3 + conv1x1(folded into staging) + biases + up(ms) ----------------
// 16x32 tile, 512 threads, 1 px/thread, grid 1024 -> 4 blocks/CU, up to 32 waves/CU.
// Staging positions fixed per thread (hoisted); 1x1 conv accumulated in VGPRs during staging.
#define CCH 8
__global__ __launch_bounds__(512, 6) void k_conv(const float* __restrict__ feat,
                                                 const float* __restrict__ V,
                                                 const float* __restrict__ ms,
                                                 const float* __restrict__ wbuf,
                                                 const float* __restrict__ b_fine,
                                                 const float* __restrict__ b_res,
                                                 const float* __restrict__ hr,
                                                 const float* __restrict__ attn,
                                                 float* __restrict__ out) {
    __shared__ __align__(16) float s_in[CCH][648];   // 18 rows x 36 (34 halo + 2 pad)
    __shared__ __align__(16) float s_acc[4][512];    // 1x1 partials, interior 16x32
    int bid = blockIdx.x;                 // 1024 = b(32) * tile(32)
    int b   = bid >> 5;
    int t32 = bid & 31;
    int ty0 = (t32 >> 2) << 4;
    int tx0 = (t32 & 3) << 5;
    int tid = threadIdx.x;                // 0..511
    int ty  = tid >> 5, lx = tid & 31;
    int gy  = ty0 + ty, gx = tx0 + lx;

    // ---- hoisted staging-position precompute ----
    int r0 = tid / 36, c0 = tid - r0 * 36;
    int sy0 = ty0 - 1 + r0, sx0 = tx0 - 1 + c0;
    float fm0 = (c0 < 34 && sy0 >= 0 && sy0 < HH && sx0 >= 0 && sx0 < WW) ? 1.f : 0.f;
    int off0 = (min(HH - 1, max(0, sy0)) << 7) + min(WW - 1, max(0, sx0));
    bool i0in = (r0 >= 1 && r0 <= 16 && c0 >= 1 && c0 <= 32);
    float im0 = i0in ? 1.f : 0.f;
    int pix0 = (r0 - 1) * 32 + (c0 - 1);

    int i1 = tid + 512;
    bool has1 = (i1 < 648);               // tid < 136
    int r1 = i1 / 36, c1 = i1 - r1 * 36;
    int sy1 = ty0 - 1 + r1, sx1 = tx0 - 1 + c1;
    float fm1 = (has1 && c1 < 34 && sy1 < HH && sx1 >= 0 && sx1 < WW) ? 1.f : 0.f;
    int off1 = (min(HH - 1, sy1) << 7) + min(WW - 1, max(0, sx1));
    bool i1in = (has1 && r1 >= 1 && r1 <= 16 && c1 >= 1 && c1 <= 32);
    float im1 = i1in ? 1.f : 0.f;
    int pix1 = (r1 - 1) * 32 + (c1 - 1);

    float a0 = 0.f, a1 = 0.f, a2 = 0.f, a3 = 0.f;
    float x10[4] = {0.f, 0.f, 0.f, 0.f};
    float x11[4] = {0.f, 0.f, 0.f, 0.f};

    for (int cb = 0; cb < NFEAT; cb += CCH) {
        __syncthreads();
        // ---- stage chunk + fold 1x1 ----
#pragma unroll
        for (int cc = 0; cc < CCH; ++cc) {
            int c = cb + cc;
            const float* wc = wbuf + c * 48;          // uniform -> s_load
            const float* fsrc = feat + (((size_t)b * NFEAT + c) << 14);
            float wr0 = wc[36], wr1 = wc[37], wr2 = wc[38], wr3 = wc[39];
            if (c < C1c) {
                const float* hsrc = hr + (((size_t)b * C1c + c) << 14);
                float f0 = fsrc[off0], h0 = hsrc[off0];
                s_in[cc][tid] = h0 * fm0;
                float ff0 = f0 * im0;
                x10[0] += wr0 * ff0; x10[1] += wr1 * ff0; x10[2] += wr2 * ff0; x10[3] += wr3 * ff0;
                if (has1) {
                    float f1 = fsrc[off1], h1 = hsrc[off1];
                    s_in[cc][i1] = h1 * fm1;
                    float ff1 = f1 * im1;
                    x11[0] += wr0 * ff1; x11[1] += wr1 * ff1; x11[2] += wr2 * ff1; x11[3] += wr3 * ff1;
                }
            } else {
                float am = attn[b * LRC + (c - C1c)];
                const float* vsrc = V + (((size_t)b * NFEAT + c) << 14);
                float f0 = fsrc[off0], v0 = vsrc[off0];
                s_in[cc][tid] = f0 * v0 * (am * fm0);
                float ff0 = f0 * im0;
                x10[0] += wr0 * ff0; x10[1] += wr1 * ff0; x10[2] += wr2 * ff0; x10[3] += wr3 * ff0;
                if (has1) {
                    float f1 = fsrc[off1], v1 = vsrc[off1];
                    s_in[cc][i1] = f1 * v1 * (am * fm1);
                    float ff1 = f1 * im1;
                    x11[0] += wr0 * ff1; x11[1] += wr1 * ff1; x11[2] += wr2 * ff1; x11[3] += wr3 * ff1;
                }
            }
        }
        __syncthreads();
        // ---- compute chunk (3x3 conv) ----
        int base = ty * 36 + lx;
#pragma unroll
        for (int cc = 0; cc < CCH; ++cc) {
            int c = cb + cc;
            const float* wc = wbuf + c * 48;          // uniform -> s_load
            const float* sp = &s_in[cc][base];
            float t00 = sp[0],  t01 = sp[1],  t02 = sp[2];
            float t10 = sp[36], t11 = sp[37], t12 = sp[38];
            float t20 = sp[72], t21 = sp[73], t22 = sp[74];
            a0 += wc[0] * t00 + wc[1] * t01 + wc[2] * t02
                + wc[3] * t10 + wc[4] * t11 + wc[5] * t12
                + wc[6] * t20 + wc[7] * t21 + wc[8] * t22;
            a1 += wc[9]  * t00 + wc[10] * t01 + wc[11] * t02
                + wc[12] * t10 + wc[13] * t11 + wc[14] * t12
                + wc[15] * t20 + wc[16] * t21 + wc[17] * t22;
            a2 += wc[18] * t00 + wc[19] * t01 + wc[20] * t02
                + wc[21] * t10 + wc[22] * t11 + wc[23] * t12
                + wc[24] * t20 + wc[25] * t21 + wc[26] * t22;
            a3 += wc[27] * t00 + wc[28] * t01 + wc[29] * t02
                + wc[30] * t10 + wc[31] * t11 + wc[32] * t12
                + wc[33] * t20 + wc[34] * t21 + wc[35] * t22;
        }
    }
    // ---- publish 1x1 partials ----
    if (i0in) { s_acc[0][pix0] = x10[0]; s_acc[1][pix0] = x10[1]; s_acc[2][pix0] = x10[2]; s_acc[3][pix0] = x10[3]; }
    if (i1in) { s_acc[0][pix1] = x11[0]; s_acc[1][pix1] = x11[1]; s_acc[2][pix1] = x11[2]; s_acc[3][pix1] = x11[3]; }
    __syncthreads();
    int pix = ty * 32 + lx;
    float acc1x1[4] = { s_acc[0][pix], s_acc[1][pix], s_acc[2][pix], s_acc[3][pix] };
    float av[4] = { a0, a1, a2, a3 };
    // ---- epilogue: biases + bilinear upsample of ms + store ----
    float syf = (gy + 0.5f) * 0.25f - 0.5f;
    int y0i = (int)floorf(syf); float fy = syf - (float)y0i;
    int y0c = min(31, max(0, y0i)), y1c = min(31, max(0, y0i + 1));
    float sxf = (gx + 0.5f) * 0.25f - 0.5f;
    int x0i = (int)floorf(sxf); float fx = sxf - (float)x0i;
    int x0c = min(31, max(0, x0i)), x1c = min(31, max(0, x0i + 1));
#pragma unroll
    for (int o = 0; o < 4; ++o) {
        const float* mb = ms + ((size_t)(b * 4 + o) << 10);
        float m00 = mb[(y0c << 5) + x0c], m01 = mb[(y0c << 5) + x1c];
        float m10 = mb[(y1c << 5) + x0c], m11 = mb[(y1c << 5) + x1c];
        float up = (m00 * (1.f - fx) + m01 * fx) * (1.f - fy)
                 + (m10 * (1.f - fx) + m11 * fx) * fy;
        out[((size_t)(b * 4 + o) << 14) + (gy << 7) + gx] =
            av[o] + acc1x1[o] + b_fine[o] + b_res[o] + up;
    }
}

extern "C" void kernel_launch(void* const* d_in, const int* in_sizes, int n_in,
                              void* d_out, int out_size, void* d_ws, size_t ws_size,
                              hipStream_t stream) {
    (void)in_sizes; (void)n_in; (void)out_size; (void)ws_size;
    const float* ms     = (const float*)d_in[0];
    const float* feat   = (const float*)d_in[1];
    const float* V      = (const float*)d_in[2];
    const float* logits = (const float*)d_in[3];
    const float* sigx   = (const float*)d_in[4];
    const float* sigy   = (const float*)d_in[5];
    const float* opac   = (const float*)d_in[6];
    const float* rho    = (const float*)d_in[7];
    const float* w_v2   = (const float*)d_in[8];
    const float* w_fine = (const float*)d_in[9];
    const float* b_fine = (const float*)d_in[10];
    const float* w_res  = (const float*)d_in[11];
    const float* b_res  = (const float*)d_in[12];
    float* ws  = (float*)d_ws;
    float* out = (float*)d_out;

    hipMemsetAsync(ws + OFF_PM, 0, (size_t)NP * NQ * sizeof(float), stream);
    k_phase1<<<512 + NBATCH * LRC, 256, 0, stream>>>(logits, feat, ws + OFF_PM, ws + OFF_GAP);
    k_small<<<1, 256, 0, stream>>>(ws + OFF_PM, ws + OFF_GAP, sigx, sigy, opac, rho, w_v2,
                                   w_fine, w_res, ws + OFF_K, ws + OFF_ATTN, ws + OFF_WB);
    k_hr<<<512, 256, 0, stream>>>(feat, V, ws + OFF_K, ws + OFF_HR);
    k_conv<<<1024, 512, 0, stream>>>(feat, V, ms, ws + OFF_WB, b_fine, b_res,
                                     ws + OFF_HR, ws + OFF_ATTN, out);
}

// Round 5
// 286.105 us; speedup vs baseline: 1.0124x; 1.0124x over previous
//
#include <hip/hip_runtime.h>

#define NBATCH 32
#define NFEAT 48
#define C1c 6
#define LRC 42
#define HH 128
#define WW 128
#define HWSZ 16384
#define NP 81
#define NQ 64

// workspace layout (in floats)
#define OFF_PM   0                      // 81*64 = 5184
#define OFF_GAP  5184                   // 32*42 = 1344
#define OFF_K    6528                   // 64*64 = 4096
#define OFF_ATTN 10624                  // 1344
#define OFF_WB   11968                  // 48*48 = 2304 rearranged weights
#define OFF_HR   14272                  // 32*6*16384 = 3145728

// ---------------- Phase 1 (merged): softmax->pm binning  +  gap sums ----------------
__global__ __launch_bounds__(256, 2) void k_phase1(const float* __restrict__ logits,
                                                   const float* __restrict__ feat,
                                                   float* __restrict__ pm_sum,
                                                   float* __restrict__ gap) {
    int bid = blockIdx.x;
    int tid = threadIdx.x;
    if (bid < 512) {
        // per-pixel softmax over 81 ch, binned into pm_sum[81][64]
        int b   = bid >> 4;
        int ygp = (bid >> 2) & 3;
        int qq  = bid & 3;
        int x   = tid & 127;
        int yg  = ygp * 2 + (tid >> 7);
        float acc[NP];
#pragma unroll
        for (int p = 0; p < NP; ++p) acc[p] = 0.f;
        for (int k = 0; k < 4; ++k) {
            int y = yg + 8 * (qq * 4 + k);
            const float* base = logits + (size_t)b * NP * HWSZ + (y << 7) + x;
            float ev[NP];
            float s = 0.f;
#pragma unroll
            for (int p = 0; p < NP; ++p) { ev[p] = __expf(base[(size_t)p * HWSZ]); s += ev[p]; }
            float inv = 1.f / s;
#pragma unroll
            for (int p = 0; p < NP; ++p) acc[p] += ev[p] * inv;
        }
        int lane = tid & 63;
#pragma unroll
        for (int p = 0; p < NP; ++p) {
            float e = acc[p];
            e += __shfl_xor(e, 8);
            e += __shfl_xor(e, 16);
            e += __shfl_xor(e, 32);
            if (lane < 8) atomicAdd(&pm_sum[p * NQ + (yg << 3) + lane], e);
        }
    } else {
        // gap_sum[b][c] = sum over HxW of feat[b, 6+c]
        int gid = bid - 512;
        int b = gid / LRC, c = gid % LRC;
        const float4* p4 = (const float4*)(feat + ((size_t)b * NFEAT + C1c + c) * HWSZ);
        float s = 0.f;
        for (int i = tid; i < HWSZ / 4; i += 256) {
            float4 v = p4[i];
            s += (v.x + v.y) + (v.z + v.w);
        }
        s += __shfl_xor(s, 1);  s += __shfl_xor(s, 2);  s += __shfl_xor(s, 4);
        s += __shfl_xor(s, 8);  s += __shfl_xor(s, 16); s += __shfl_xor(s, 32);
        __shared__ float w4[4];
        if ((tid & 63) == 0) w4[tid >> 6] = s;
        __syncthreads();
        if (tid == 0) gap[gid] = w4[0] + w4[1] + w4[2] + w4[3];
    }
}

// ---------------- K3: build K (64x64), attn (32x42), and rearranged weights wbuf[48][48] ----------------
__global__ __launch_bounds__(256) void k_small(const float* __restrict__ pm_sum,
                                               const float* __restrict__ gap_sum,
                                               const float* __restrict__ sigx,
                                               const float* __restrict__ sigy,
                                               const float* __restrict__ opac,
                                               const float* __restrict__ rho,
                                               const float* __restrict__ w_v2,
                                               const float* __restrict__ w_fine,
                                               const float* __restrict__ w_res,
                                               float* __restrict__ Kmat,
                                               float* __restrict__ attn,
                                               float* __restrict__ wbuf) {
    int tid = threadIdx.x;
    if (tid < 64) {
        int q = tid;
        float wsx = 0.f, wsy = 0.f, wop = 0.f, wr = 0.f;
        for (int p = 0; p < NP; ++p) {
            float pv = pm_sum[p * NQ + q] * (1.f / 8192.f);
            wsx += sigx[p] * pv;
            wsy += sigy[p] * pv;
            wop += opac[p] * pv;
            wr  += rho[p]  * pv;
        }
        float a = wsx * wsx, d = wsy * wsy, bc = wr * wsx * wsy;
        float det = a * d - bc * bc;
        float i00 = d / det, i01 = -bc / det, i11 = a / det;
        int iq = q >> 3, jq = q & 7;
        for (int h = 0; h < 8; ++h)
            for (int w = 0; w < 8; ++w) {
                int ki = h - iq + 2, kj = w - jq + 2;
                float val = 0.f;
                if (ki >= 0 && ki < 5 && kj >= 0 && kj < 5) {
                    float xx = -5.f + 2.5f * ki, yy = -5.f + 2.5f * kj;
                    val = wop * __expf(-0.5f * (i00 * xx * xx + 2.f * i01 * xx * yy + i11 * yy * yy));
                }
                Kmat[(q << 6) + (h << 3) + w] = val;
            }
    }
    for (int i = tid; i < NBATCH * LRC; i += 256) {
        int b = i / LRC, co = i % LRC;
        float s = 0.f;
        for (int ci = 0; ci < LRC; ++ci) s += w_v2[co * LRC + ci] * gap_sum[b * LRC + ci];
        s *= (1.f / 16384.f);
        attn[i] = 1.f / (1.f + __expf(-s));
    }
    // wbuf[c*48 + o*9 + t] = w_fine[o][c][t];  wbuf[c*48 + 36 + o] = w_res[o][c]
    for (int i = tid; i < NFEAT * 48; i += 256) {
        int c = i / 48, j = i - c * 48;
        float v = 0.f;
        if (j < 36) v = w_fine[(j / 9) * (NFEAT * 9) + c * 9 + (j % 9)];
        else if (j < 40) v = w_res[(j - 36) * NFEAT + c];
        wbuf[i] = v;
    }
}

// ---------------- K4: hr = (colors @ K) * V1 ----------------
__global__ __launch_bounds__(256) void k_hr(const float* __restrict__ feat,
                                            const float* __restrict__ V,
                                            const float* __restrict__ Kmat,
                                            float* __restrict__ hrbuf) {
    __shared__ __align__(16) float lK[64 * 96];     // [q][h*12 + j], j<8 used
    __shared__ __align__(16) float lF[3 * 16 * 128];
    int bid   = blockIdx.x;
    int b     = bid >> 4;
    int strip = (bid >> 1) & 7;
    int ch    = (bid & 1) * 3;
    int y0    = strip << 4;
    int tid   = threadIdx.x;
    for (int i = tid; i < 4096; i += 256) {
        int q = i >> 6, hj = i & 63;
        lK[q * 96 + (hj >> 3) * 12 + (hj & 7)] = Kmat[i];
    }
    for (int i = tid; i < 6144; i += 256) {
        int c = i >> 11, rem = i & 2047;
        lF[i] = feat[(((size_t)b * NFEAT + ch + c) << 14) + (((size_t)y0 + (rem >> 7)) << 7) + (rem & 127)];
    }
    __syncthreads();
    int tile = tid >> 3, hrow = tid & 7;
    int tr = tile >> 4, tx = tile & 15;
    float acc[3][8];
#pragma unroll
    for (int c = 0; c < 3; ++c)
#pragma unroll
        for (int j = 0; j < 8; ++j) acc[c][j] = 0.f;
    int fbase = (tr << 3) * 128 + (tx << 3);
    for (int q = 0; q < 64; ++q) {
        int iq = q >> 3, jq = q & 7;
        const float4 k0 = *(const float4*)&lK[q * 96 + hrow * 12];
        const float4 k1 = *(const float4*)&lK[q * 96 + hrow * 12 + 4];
#pragma unroll
        for (int c = 0; c < 3; ++c) {
            float col = lF[(c << 11) + fbase + (iq << 7) + jq];
            acc[c][0] += col * k0.x; acc[c][1] += col * k0.y;
            acc[c][2] += col * k0.z; acc[c][3] += col * k0.w;
            acc[c][4] += col * k1.x; acc[c][5] += col * k1.y;
            acc[c][6] += col * k1.z; acc[c][7] += col * k1.w;
        }
    }
    int y = y0 + (tr << 3) + hrow;
#pragma unroll
    for (int c = 0; c < 3; ++c) {
        const float4* vp = (const float4*)(V + (((size_t)b * NFEAT + ch + c) << 14) + ((size_t)y << 7) + (tx << 3));
        float4 v0 = vp[0], v1 = vp[1];
        float4 r0, r1;
        r0.x = acc[c][0] * v0.x; r0.y = acc[c][1] * v0.y; r0.z = acc[c][2] * v0.z; r0.w = acc[c][3] * v0.w;
        r1.x = acc[c][4] * v1.x; r1.y = acc[c][5] * v1.y; r1.z = acc[c][6] * v1.z; r1.w = acc[c][7] * v1.w;
        float4* op = (float4*)(hrbuf + (((size_t)b * C1c + ch + c) << 14) + ((size_t)y << 7) + (tx << 3));
        op[0] = r0; op[1] = r1;
    }
}

// ---------------- K5: fused conv3x3 + conv1x1(folded) + biases + up(ms) ----------------
// 32x32 tile, 256 threads, 4 px/thread (1 row x 4 cols, aligned). CCH=6 -> 32.6KB LDS,
// 4 blocks/CU, 16 waves/CU. All LDS accesses aligned b128/b64/b32; stride 40.
#define CCH 6
__global__ __launch_bounds__(256, 4) void k_conv(const float* __restrict__ feat,
                                                 const float* __restrict__ V,
                                                 const float* __restrict__ ms,
                                                 const float* __restrict__ wbuf,
                                                 const float* __restrict__ b_fine,
                                                 const float* __restrict__ b_res,
                                                 const float* __restrict__ hrbuf,
                                                 const float* __restrict__ attn,
                                                 float* __restrict__ out) {
    __shared__ __align__(16) float s_in[CCH][34 * 40];   // cols 3..36 hold cl 0..33
    int bid = blockIdx.x;                 // 512 = b(32) * tile(16)
    int b   = bid >> 4;
    int t16 = bid & 15;
    int ty0 = (t16 >> 2) << 5;
    int tx0 = (t16 & 3) << 5;
    int tid = threadIdx.x;
    int ty  = tid >> 3;                   // 0..31
    int tx  = tid & 7;                    // 0..7
    int gy  = ty0 + ty;
    int gx0 = tx0 + 4 * tx;
    int own_off = (gy << 7) + gx0;
    int own_lds = (ty + 1) * 40 + 4 + 4 * tx;

    // ---- halo meta (132 ring positions, first 132 threads) ----
    bool hhas = tid < 132;
    int hrr, hcc;
    if (tid < 34)       { hrr = 0;         hcc = tid; }
    else if (tid < 68)  { hrr = 33;        hcc = tid - 34; }
    else if (tid < 100) { hrr = tid - 67;  hcc = 0; }
    else                { hrr = tid - 99;  hcc = 33; }
    int hsy = ty0 - 1 + hrr, hsx = tx0 - 1 + hcc;
    float hfm = (hsy >= 0 && hsy < HH && hsx >= 0 && hsx < WW) ? 1.f : 0.f;
    int hoff = (min(HH - 1, max(0, hsy)) << 7) + min(WW - 1, max(0, hsx));
    int hlds = hrr * 40 + hcc + 3;

    float a[4][4];
#pragma unroll
    for (int j = 0; j < 4; ++j)
#pragma unroll
        for (int o = 0; o < 4; ++o) a[j][o] = 0.f;

    for (int cb = 0; cb < NFEAT; cb += CCH) {
        __syncthreads();
        // ---- stage chunk + fold 1x1 ----
#pragma unroll
        for (int cc = 0; cc < CCH; ++cc) {
            int c = cb + cc;
            const float* wc   = wbuf + c * 48;                      // uniform -> s_load
            const float* fsrc = feat + (((size_t)b * NFEAT + c) << 14);
            float4 f4 = *(const float4*)&fsrc[own_off];
            float4 st;
            if (c < C1c) {
                const float* hsrc = hrbuf + (((size_t)b * C1c + c) << 14);
                st = *(const float4*)&hsrc[own_off];
                if (hhas) s_in[cc][hlds] = hsrc[hoff] * hfm;
            } else {
                float am = attn[b * LRC + (c - C1c)];
                const float* vsrc = V + (((size_t)b * NFEAT + c) << 14);
                float4 v4 = *(const float4*)&vsrc[own_off];
                st = make_float4(f4.x * v4.x * am, f4.y * v4.y * am,
                                 f4.z * v4.z * am, f4.w * v4.w * am);
                if (hhas) s_in[cc][hlds] = fsrc[hoff] * vsrc[hoff] * (am * hfm);
            }
            *(float4*)&s_in[cc][own_lds] = st;
            float wr0 = wc[36], wr1 = wc[37], wr2 = wc[38], wr3 = wc[39];
            a[0][0] += wr0 * f4.x; a[0][1] += wr1 * f4.x; a[0][2] += wr2 * f4.x; a[0][3] += wr3 * f4.x;
            a[1][0] += wr0 * f4.y; a[1][1] += wr1 * f4.y; a[1][2] += wr2 * f4.y; a[1][3] += wr3 * f4.y;
            a[2][0] += wr0 * f4.z; a[2][1] += wr1 * f4.z; a[2][2] += wr2 * f4.z; a[2][3] += wr3 * f4.z;
            a[3][0] += wr0 * f4.w; a[3][1] += wr1 * f4.w; a[3][2] += wr2 * f4.w; a[3][3] += wr3 * f4.w;
        }
        __syncthreads();
        // ---- compute chunk (3x3 conv), aligned LDS reads ----
#pragma unroll
        for (int cc = 0; cc < CCH; ++cc) {
            int c = cb + cc;
            const float* wc = wbuf + c * 48;                        // uniform -> s_load
            float t[3][6];
#pragma unroll
            for (int dy = 0; dy < 3; ++dy) {
                int row = (ty + dy) * 40 + 4 * tx;
                t[dy][0] = s_in[cc][row + 3];
                float4 m = *(const float4*)&s_in[cc][row + 4];
                t[dy][1] = m.x; t[dy][2] = m.y; t[dy][3] = m.z; t[dy][4] = m.w;
                t[dy][5] = s_in[cc][row + 8];
            }
#pragma unroll
            for (int o = 0; o < 4; ++o) {
                float w00 = wc[o * 9 + 0], w01 = wc[o * 9 + 1], w02 = wc[o * 9 + 2];
                float w10 = wc[o * 9 + 3], w11 = wc[o * 9 + 4], w12 = wc[o * 9 + 5];
                float w20 = wc[o * 9 + 6], w21 = wc[o * 9 + 7], w22 = wc[o * 9 + 8];
#pragma unroll
                for (int j = 0; j < 4; ++j) {
                    a[j][o] += w00 * t[0][j] + w01 * t[0][j + 1] + w02 * t[0][j + 2]
                             + w10 * t[1][j] + w11 * t[1][j + 1] + w12 * t[1][j + 2]
                             + w20 * t[2][j] + w21 * t[2][j + 1] + w22 * t[2][j + 2];
                }
            }
        }
    }
    // ---- epilogue: biases + bilinear upsample of ms + store ----
    float syf = (gy + 0.5f) * 0.25f - 0.5f;
    int y0i = (int)floorf(syf); float fy = syf - (float)y0i;
    int y0c = min(31, max(0, y0i)), y1c = min(31, max(0, y0i + 1));
    float fxv[4]; int x0v[4], x1v[4];
#pragma unroll
    for (int j = 0; j < 4; ++j) {
        float sxf = (gx0 + j + 0.5f) * 0.25f - 0.5f;
        int x0i = (int)floorf(sxf);
        fxv[j] = sxf - (float)x0i;
        x0v[j] = min(31, max(0, x0i));
        x1v[j] = min(31, max(0, x0i + 1));
    }
#pragma unroll
    for (int o = 0; o < 4; ++o) {
        const float* mb = ms + ((size_t)(b * 4 + o) << 10);
        float addc = b_fine[o] + b_res[o];
        float res[4];
#pragma unroll
        for (int j = 0; j < 4; ++j) {
            float m00 = mb[(y0c << 5) + x0v[j]], m01 = mb[(y0c << 5) + x1v[j]];
            float m10 = mb[(y1c << 5) + x0v[j]], m11 = mb[(y1c << 5) + x1v[j]];
            float up = (m00 * (1.f - fxv[j]) + m01 * fxv[j]) * (1.f - fy)
                     + (m10 * (1.f - fxv[j]) + m11 * fxv[j]) * fy;
            res[j] = a[j][o] + addc + up;
        }
        *(float4*)&out[((size_t)(b * 4 + o) << 14) + own_off] =
            make_float4(res[0], res[1], res[2], res[3]);
    }
}

extern "C" void kernel_launch(void* const* d_in, const int* in_sizes, int n_in,
                              void* d_out, int out_size, void* d_ws, size_t ws_size,
                              hipStream_t stream) {
    (void)in_sizes; (void)n_in; (void)out_size; (void)ws_size;
    const float* ms     = (const float*)d_in[0];
    const float* feat   = (const float*)d_in[1];
    const float* V      = (const float*)d_in[2];
    const float* logits = (const float*)d_in[3];
    const float* sigx   = (const float*)d_in[4];
    const float* sigy   = (const float*)d_in[5];
    const float* opac   = (const float*)d_in[6];
    const float* rho    = (const float*)d_in[7];
    const float* w_v2   = (const float*)d_in[8];
    const float* w_fine = (const float*)d_in[9];
    const float* b_fine = (const float*)d_in[10];
    const float* w_res  = (const float*)d_in[11];
    const float* b_res  = (const float*)d_in[12];
    float* ws  = (float*)d_ws;
    float* out = (float*)d_out;

    hipMemsetAsync(ws + OFF_PM, 0, (size_t)NP * NQ * sizeof(float), stream);
    k_phase1<<<512 + NBATCH * LRC, 256, 0, stream>>>(logits, feat, ws + OFF_PM, ws + OFF_GAP);
    k_small<<<1, 256, 0, stream>>>(ws + OFF_PM, ws + OFF_GAP, sigx, sigy, opac, rho, w_v2,
                                   w_fine, w_res, ws + OFF_K, ws + OFF_ATTN, ws + OFF_WB);
    k_hr<<<512, 256, 0, stream>>>(feat, V, ws + OFF_K, ws + OFF_HR);
    k_conv<<<512, 256, 0, stream>>>(feat, V, ms, ws + OFF_WB, b_fine, b_res,
                                    ws + OFF_HR, ws + OFF_ATTN, out);
}

// Round 6
// 206.807 us; speedup vs baseline: 1.4006x; 1.3834x over previous
//
#include <hip/hip_runtime.h>

#define NBATCH 32
#define NFEAT 48
#define C1c 6
#define LRC 42
#define HH 128
#define WW 128
#define HWSZ 16384
#define NP 81
#define NQ 64

// workspace layout (in floats)
#define OFF_PM   0                      // 81*64 = 5184
#define OFF_GAP  5184                   // 32*42 = 1344  (contiguous after PM -> one memset)
#define OFF_K    6528                   // 64*64 = 4096
#define OFF_ATTN 10624                  // 1344
#define OFF_WB   11968                  // 48*48 = 2304 rearranged weights
#define OFF_HR   14272                  // 32*6*16384 = 3145728

// ---------------- Phase 1: A) softmax->pm binning  B) gap sums + 1x1 base + up(ms) ----------------
__global__ __launch_bounds__(256, 2) void k_phase1(const float* __restrict__ logits,
                                                   const float* __restrict__ feat,
                                                   const float* __restrict__ ms,
                                                   const float* __restrict__ w_res,
                                                   const float* __restrict__ b_fine,
                                                   const float* __restrict__ b_res,
                                                   float* __restrict__ pm_sum,
                                                   float* __restrict__ gap,
                                                   float* __restrict__ out) {
    int bid = blockIdx.x;
    int tid = threadIdx.x;
    if (bid < 512) {
        // ---- A: per-pixel softmax over 81 ch, binned into pm_sum[81][64] ----
        int b   = bid >> 4;
        int ygp = (bid >> 2) & 3;
        int qq  = bid & 3;
        int x   = tid & 127;
        int yg  = ygp * 2 + (tid >> 7);
        float acc[NP];
#pragma unroll
        for (int p = 0; p < NP; ++p) acc[p] = 0.f;
        for (int k = 0; k < 4; ++k) {
            int y = yg + 8 * (qq * 4 + k);
            const float* base = logits + (size_t)b * NP * HWSZ + (y << 7) + x;
            float ev[NP];
            float s = 0.f;
#pragma unroll
            for (int p = 0; p < NP; ++p) { ev[p] = __expf(base[(size_t)p * HWSZ]); s += ev[p]; }
            float inv = 1.f / s;
#pragma unroll
            for (int p = 0; p < NP; ++p) acc[p] += ev[p] * inv;
        }
        int lane = tid & 63;
#pragma unroll
        for (int p = 0; p < NP; ++p) {
            float e = acc[p];
            e += __shfl_xor(e, 8);
            e += __shfl_xor(e, 16);
            e += __shfl_xor(e, 32);
            if (lane < 8) atomicAdd(&pm_sum[p * NQ + (yg << 3) + lane], e);
        }
    } else {
        // ---- B: 256 blocks = b(32) x strip(8 of 16 rows). Each thread: 8 px in one row.
        int gid = bid - 512;
        int b     = gid >> 3;
        int strip = gid & 7;
        int row = (strip << 4) + (tid >> 4);
        int x0  = (tid & 15) << 3;
        int poff = (row << 7) + x0;
        int lane = tid & 63;
        const float* fb = feat + (((size_t)b * NFEAT) << 14);
        float a[8][4];
#pragma unroll
        for (int j = 0; j < 8; ++j)
#pragma unroll
            for (int o = 0; o < 4; ++o) a[j][o] = 0.f;
        for (int c = 0; c < NFEAT; ++c) {
            const float* fp = fb + ((size_t)c << 14) + poff;
            float4 f0 = *(const float4*)fp;
            float4 f1 = *(const float4*)(fp + 4);
            float wr0 = w_res[c], wr1 = w_res[NFEAT + c], wr2 = w_res[2 * NFEAT + c], wr3 = w_res[3 * NFEAT + c];
            float px[8] = { f0.x, f0.y, f0.z, f0.w, f1.x, f1.y, f1.z, f1.w };
#pragma unroll
            for (int j = 0; j < 8; ++j) {
                a[j][0] += wr0 * px[j]; a[j][1] += wr1 * px[j];
                a[j][2] += wr2 * px[j]; a[j][3] += wr3 * px[j];
            }
            if (c >= C1c) {
                float s = (f0.x + f0.y + f0.z + f0.w) + (f1.x + f1.y + f1.z + f1.w);
                s += __shfl_xor(s, 1);  s += __shfl_xor(s, 2);  s += __shfl_xor(s, 4);
                s += __shfl_xor(s, 8);  s += __shfl_xor(s, 16); s += __shfl_xor(s, 32);
                if (lane == 0) atomicAdd(&gap[b * LRC + (c - C1c)], s);
            }
        }
        // epilogue: biases + bilinear up(ms), write base to out
        float syf = (row + 0.5f) * 0.25f - 0.5f;
        int y0i = (int)floorf(syf); float fy = syf - (float)y0i;
        int y0c = min(31, max(0, y0i)), y1c = min(31, max(0, y0i + 1));
        float fxv[8]; int x0v[8], x1v[8];
#pragma unroll
        for (int j = 0; j < 8; ++j) {
            float sxf = (x0 + j + 0.5f) * 0.25f - 0.5f;
            int x0i = (int)floorf(sxf);
            fxv[j] = sxf - (float)x0i;
            x0v[j] = min(31, max(0, x0i));
            x1v[j] = min(31, max(0, x0i + 1));
        }
#pragma unroll
        for (int o = 0; o < 4; ++o) {
            const float* mb = ms + ((size_t)(b * 4 + o) << 10);
            float addc = b_fine[o] + b_res[o];
            float res[8];
#pragma unroll
            for (int j = 0; j < 8; ++j) {
                float m00 = mb[(y0c << 5) + x0v[j]], m01 = mb[(y0c << 5) + x1v[j]];
                float m10 = mb[(y1c << 5) + x0v[j]], m11 = mb[(y1c << 5) + x1v[j]];
                float up = (m00 * (1.f - fxv[j]) + m01 * fxv[j]) * (1.f - fy)
                         + (m10 * (1.f - fxv[j]) + m11 * fxv[j]) * fy;
                res[j] = a[j][o] + addc + up;
            }
            float* op = out + (((size_t)(b * 4 + o)) << 14) + poff;
            *(float4*)op = make_float4(res[0], res[1], res[2], res[3]);
            *(float4*)(op + 4) = make_float4(res[4], res[5], res[6], res[7]);
        }
    }
}

// ---------------- K3: build K (64x64), attn (32x42), and rearranged weights wbuf[48][48] ----------------
__global__ __launch_bounds__(256) void k_small(const float* __restrict__ pm_sum,
                                               const float* __restrict__ gap_sum,
                                               const float* __restrict__ sigx,
                                               const float* __restrict__ sigy,
                                               const float* __restrict__ opac,
                                               const float* __restrict__ rho,
                                               const float* __restrict__ w_v2,
                                               const float* __restrict__ w_fine,
                                               const float* __restrict__ w_res,
                                               float* __restrict__ Kmat,
                                               float* __restrict__ attn,
                                               float* __restrict__ wbuf) {
    int tid = threadIdx.x;
    if (tid < 64) {
        int q = tid;
        float wsx = 0.f, wsy = 0.f, wop = 0.f, wr = 0.f;
        for (int p = 0; p < NP; ++p) {
            float pv = pm_sum[p * NQ + q] * (1.f / 8192.f);
            wsx += sigx[p] * pv;
            wsy += sigy[p] * pv;
            wop += opac[p] * pv;
            wr  += rho[p]  * pv;
        }
        float a = wsx * wsx, d = wsy * wsy, bc = wr * wsx * wsy;
        float det = a * d - bc * bc;
        float i00 = d / det, i01 = -bc / det, i11 = a / det;
        int iq = q >> 3, jq = q & 7;
        for (int h = 0; h < 8; ++h)
            for (int w = 0; w < 8; ++w) {
                int ki = h - iq + 2, kj = w - jq + 2;
                float val = 0.f;
                if (ki >= 0 && ki < 5 && kj >= 0 && kj < 5) {
                    float xx = -5.f + 2.5f * ki, yy = -5.f + 2.5f * kj;
                    val = wop * __expf(-0.5f * (i00 * xx * xx + 2.f * i01 * xx * yy + i11 * yy * yy));
                }
                Kmat[(q << 6) + (h << 3) + w] = val;
            }
    }
    for (int i = tid; i < NBATCH * LRC; i += 256) {
        int b = i / LRC, co = i % LRC;
        float s = 0.f;
        for (int ci = 0; ci < LRC; ++ci) s += w_v2[co * LRC + ci] * gap_sum[b * LRC + ci];
        s *= (1.f / 16384.f);
        attn[i] = 1.f / (1.f + __expf(-s));
    }
    for (int i = tid; i < NFEAT * 48; i += 256) {
        int c = i / 48, j = i - c * 48;
        float v = 0.f;
        if (j < 36) v = w_fine[(j / 9) * (NFEAT * 9) + c * 9 + (j % 9)];
        else if (j < 40) v = w_res[(j - 36) * NFEAT + c];
        wbuf[i] = v;
    }
}

// ---------------- K4: hr = (colors @ K) * V1 ----------------
// grid 768 = b(32) * strip(8 of 16 rows) * chgrp(3 of 2 channels); 3 blocks/CU, all resident.
__global__ __launch_bounds__(256) void k_hr(const float* __restrict__ feat,
                                            const float* __restrict__ V,
                                            const float* __restrict__ Kmat,
                                            float* __restrict__ hrbuf) {
    __shared__ __align__(16) float lK[4096];          // [q][pos] packed; reads broadcast
    __shared__ __align__(16) float lF[2 * 16 * 128];
    int bid = blockIdx.x;
    int b   = bid / 24;
    int r   = bid - b * 24;
    int strip = r / 3;
    int ch  = (r - strip * 3) * 2;
    int y0  = strip << 4;
    int tid = threadIdx.x;
    {
        const float4* ks = (const float4*)Kmat;
        float4* kd = (float4*)lK;
        for (int i = tid; i < 1024; i += 256) kd[i] = ks[i];
        float4* fd = (float4*)lF;
        const float* fb = feat + (((size_t)b * NFEAT + ch) << 14) + (y0 << 7);
        for (int i = tid; i < 1024; i += 256) {
            int c = i >> 9, rem = i & 511;
            fd[i] = *(const float4*)&fb[((size_t)c << 14) + (rem << 2)];
        }
    }
    __syncthreads();
    int tile = tid >> 3, hrow = tid & 7;
    int tr = tile >> 4, tx = tile & 15;
    float acc[2][8];
#pragma unroll
    for (int c = 0; c < 2; ++c)
#pragma unroll
        for (int j = 0; j < 8; ++j) acc[c][j] = 0.f;
    int fbase = (tr << 3) * 128 + (tx << 3);
    for (int q = 0; q < 64; ++q) {
        int iq = q >> 3, jq = q & 7;
        const float4 k0 = *(const float4*)&lK[(q << 6) + (hrow << 3)];
        const float4 k1 = *(const float4*)&lK[(q << 6) + (hrow << 3) + 4];
#pragma unroll
        for (int c = 0; c < 2; ++c) {
            float col = lF[(c << 11) + fbase + (iq << 7) + jq];
            acc[c][0] += col * k0.x; acc[c][1] += col * k0.y;
            acc[c][2] += col * k0.z; acc[c][3] += col * k0.w;
            acc[c][4] += col * k1.x; acc[c][5] += col * k1.y;
            acc[c][6] += col * k1.z; acc[c][7] += col * k1.w;
        }
    }
    int y = y0 + (tr << 3) + hrow;
#pragma unroll
    for (int c = 0; c < 2; ++c) {
        const float4* vp = (const float4*)(V + (((size_t)b * NFEAT + ch + c) << 14) + ((size_t)y << 7) + (tx << 3));
        float4 v0 = vp[0], v1 = vp[1];
        float4 r0, r1;
        r0.x = acc[c][0] * v0.x; r0.y = acc[c][1] * v0.y; r0.z = acc[c][2] * v0.z; r0.w = acc[c][3] * v0.w;
        r1.x = acc[c][4] * v1.x; r1.y = acc[c][5] * v1.y; r1.z = acc[c][6] * v1.z; r1.w = acc[c][7] * v1.w;
        float4* op = (float4*)(hrbuf + (((size_t)b * C1c + ch + c) << 14) + ((size_t)y << 7) + (tx << 3));
        op[0] = r0; op[1] = r1;
    }
}

// ---------------- K5: conv3x3 only (RMW onto 1x1 base) ----------------
// 16x32 tile, 256 threads, 2 px/thread (1 row x 2 cols), rolled CCH=8 chunks,
// grid 1024 (XCD-swizzled), launch_bounds(256,4): v3's proven no-scratch shell.
#define CCH 8
__global__ __launch_bounds__(256, 4) void k_conv(const float* __restrict__ feat,
                                                 const float* __restrict__ V,
                                                 const float* __restrict__ wbuf,
                                                 const float* __restrict__ hrbuf,
                                                 const float* __restrict__ attn,
                                                 float* __restrict__ out) {
    __shared__ __align__(16) float s_in[CCH][18 * 40];   // col base 3: cols 3..36 = halo 0..33
    int bid0 = blockIdx.x;
    int rid  = (bid0 & 7) * 128 + (bid0 >> 3);    // bijective XCD swizzle (1024 = 8*128)
    int b    = rid >> 5;
    int t32  = rid & 31;
    int ty0  = (t32 >> 2) << 4;
    int tx0  = (t32 & 3) << 5;
    int tid  = threadIdx.x;
    int ty   = tid >> 4;                  // 0..15
    int tx   = tid & 15;                  // 0..15
    int gy   = ty0 + ty;
    int gx0  = tx0 + 2 * tx;
    int own_goff = (gy << 7) + gx0;       // aligned float2
    int own_lds  = (ty + 1) * 40 + 4 + 2 * tx;   // even -> b64 write

    // halo ring (100 positions, first 100 threads)
    bool hhas = tid < 100;
    int rr, cc;
    if (tid < 34)      { rr = 0;        cc = tid; }
    else if (tid < 68) { rr = 17;       cc = tid - 34; }
    else if (tid < 84) { rr = tid - 67; cc = 0; }
    else               { rr = tid - 83; cc = 33; }
    int hsy = ty0 - 1 + rr, hsx = tx0 - 1 + cc;
    float hfm = (hsy >= 0 && hsy < HH && hsx >= 0 && hsx < WW) ? 1.f : 0.f;
    int hoff = (min(HH - 1, max(0, hsy)) << 7) + min(WW - 1, max(0, hsx));
    int hlds = rr * 40 + 3 + cc;

    float a00 = 0.f, a01 = 0.f, a02 = 0.f, a03 = 0.f;   // px0, outs 0..3
    float a10 = 0.f, a11 = 0.f, a12 = 0.f, a13 = 0.f;   // px1

    for (int cb = 0; cb < NFEAT; cb += CCH) {
        __syncthreads();
        for (int k = 0; k < CCH; ++k) {               // rolled: low pressure
            int c = cb + k;
            if (c < C1c) {
                const float* hsrc = hrbuf + (((size_t)b * C1c + c) << 14);
                *(float2*)&s_in[k][own_lds] = *(const float2*)&hsrc[own_goff];
                if (hhas) s_in[k][hlds] = hsrc[hoff] * hfm;
            } else {
                float am = attn[b * LRC + (c - C1c)];
                const float* fsrc = feat + (((size_t)b * NFEAT + c) << 14);
                const float* vsrc = V    + (((size_t)b * NFEAT + c) << 14);
                float2 f2 = *(const float2*)&fsrc[own_goff];
                float2 v2 = *(const float2*)&vsrc[own_goff];
                *(float2*)&s_in[k][own_lds] = make_float2(f2.x * v2.x * am, f2.y * v2.y * am);
                if (hhas) s_in[k][hlds] = fsrc[hoff] * vsrc[hoff] * (am * hfm);
            }
        }
        __syncthreads();
        for (int k = 0; k < CCH; ++k) {               // rolled: low pressure
            int c = cb + k;
            const float* wc = wbuf + c * 48;          // uniform -> s_load
            int base = ty * 40 + 3 + 2 * tx;
            float tA0 = s_in[k][base];
            float2 m0 = *(const float2*)&s_in[k][base + 1];
            float tD0 = s_in[k][base + 3];
            float tA1 = s_in[k][base + 40];
            float2 m1 = *(const float2*)&s_in[k][base + 41];
            float tD1 = s_in[k][base + 43];
            float tA2 = s_in[k][base + 80];
            float2 m2 = *(const float2*)&s_in[k][base + 81];
            float tD2 = s_in[k][base + 83];
#pragma unroll
            for (int o = 0; o < 4; ++o) {
                float w0 = wc[o * 9 + 0], w1 = wc[o * 9 + 1], w2 = wc[o * 9 + 2];
                float w3 = wc[o * 9 + 3], w4 = wc[o * 9 + 4], w5 = wc[o * 9 + 5];
                float w6 = wc[o * 9 + 6], w7 = wc[o * 9 + 7], w8 = wc[o * 9 + 8];
                float r0 = w0 * tA0 + w1 * m0.x + w2 * m0.y
                         + w3 * tA1 + w4 * m1.x + w5 * m1.y
                         + w6 * tA2 + w7 * m2.x + w8 * m2.y;
                float r1 = w0 * m0.x + w1 * m0.y + w2 * tD0
                         + w3 * m1.x + w4 * m1.y + w5 * tD1
                         + w6 * m2.x + w7 * m2.y + w8 * tD2;
                if (o == 0) { a00 += r0; a10 += r1; }
                else if (o == 1) { a01 += r0; a11 += r1; }
                else if (o == 2) { a02 += r0; a12 += r1; }
                else { a03 += r0; a13 += r1; }
            }
        }
    }
    // ---- epilogue: RMW the 1x1+bias+ms base already in out ----
    float ar[4][2] = { {a00, a10}, {a01, a11}, {a02, a12}, {a03, a13} };
#pragma unroll
    for (int o = 0; o < 4; ++o) {
        float* op = out + (((size_t)(b * 4 + o)) << 14) + own_goff;
        float2 base = *(const float2*)op;
        *(float2*)op = make_float2(base.x + ar[o][0], base.y + ar[o][1]);
    }
}

extern "C" void kernel_launch(void* const* d_in, const int* in_sizes, int n_in,
                              void* d_out, int out_size, void* d_ws, size_t ws_size,
                              hipStream_t stream) {
    (void)in_sizes; (void)n_in; (void)out_size; (void)ws_size;
    const float* ms     = (const float*)d_in[0];
    const float* feat   = (const float*)d_in[1];
    const float* V      = (const float*)d_in[2];
    const float* logits = (const float*)d_in[3];
    const float* sigx   = (const float*)d_in[4];
    const float* sigy   = (const float*)d_in[5];
    const float* opac   = (const float*)d_in[6];
    const float* rho    = (const float*)d_in[7];
    const float* w_v2   = (const float*)d_in[8];
    const float* w_fine = (const float*)d_in[9];
    const float* b_fine = (const float*)d_in[10];
    const float* w_res  = (const float*)d_in[11];
    const float* b_res  = (const float*)d_in[12];
    float* ws  = (float*)d_ws;
    float* out = (float*)d_out;

    // zero pm_sum + gap (contiguous)
    hipMemsetAsync(ws + OFF_PM, 0, (size_t)(NP * NQ + NBATCH * LRC) * sizeof(float), stream);
    k_phase1<<<512 + 256, 256, 0, stream>>>(logits, feat, ms, w_res, b_fine, b_res,
                                            ws + OFF_PM, ws + OFF_GAP, out);
    k_small<<<1, 256, 0, stream>>>(ws + OFF_PM, ws + OFF_GAP, sigx, sigy, opac, rho, w_v2,
                                   w_fine, w_res, ws + OFF_K, ws + OFF_ATTN, ws + OFF_WB);
    k_hr<<<768, 256, 0, stream>>>(feat, V, ws + OFF_K, ws + OFF_HR);
    k_conv<<<1024, 256, 0, stream>>>(feat, V, ws + OFF_WB, ws + OFF_HR, ws + OFF_ATTN, out);
}